// Round 9
// baseline (345.056 us; speedup 1.0000x reference)
//
#include <hip/hip_runtime.h>
#include <hip/hip_bf16.h>
#include <cstdint>

#define TOKENS 2048
#define Dm 1024
#define Fm 4096
#define Em 8

typedef short s16x8 __attribute__((ext_vector_type(8)));
typedef float f32x4 __attribute__((ext_vector_type(4)));

#define GLOAD16(g, l) __builtin_amdgcn_global_load_lds(                     \
    (const __attribute__((address_space(1))) void*)(g),                     \
    (__attribute__((address_space(3))) void*)(l), 16, 0, 0)

__device__ __forceinline__ ushort f2bf(float f) {
  union { float f; uint32_t u; } v; v.f = f;
  uint32_t r = v.u + 0x7fffu + ((v.u >> 16) & 1u);
  return (ushort)(r >> 16);
}

// one MFMA K-step (BK=32): read swizzled frags; A elems [0,4096), B [4096,8192)
__device__ __forceinline__ void kstep(const ushort* sbuf, int aidx, int bidx,
                                      f32x4 (&acc)[4][4]) {
  s16x8 av[4], bv[4];
#pragma unroll
  for (int m = 0; m < 4; ++m)
    av[m] = *(const s16x8*)(sbuf + aidx + m * 512);
#pragma unroll
  for (int n = 0; n < 4; ++n)
    bv[n] = *(const s16x8*)(sbuf + 4096 + bidx + n * 512);
#pragma unroll
  for (int m = 0; m < 4; ++m)
#pragma unroll
    for (int n = 0; n < 4; ++n)
      acc[m][n] = __builtin_amdgcn_mfma_f32_16x16x32_bf16(av[m], bv[n], acc[m][n], 0, 0, 0);
}

// stage one 128x32 A-tile + 128x32 B-tile into sbuf (bytes [0,16384))
#define STAGE4() {                                                          \
    char* bb = (char*)sbuf;                                                 \
    GLOAD16(sA0, bb + wid * 1024);                                          \
    GLOAD16(sA1, bb + 4096 + wid * 1024);                                   \
    GLOAD16(sB0, bb + 8192 + wid * 1024);                                   \
    GLOAD16(sB1, bb + 12288 + wid * 1024);                                  \
    sA0 += 32; sA1 += 32; sB0 += 32; sB1 += 32; }

// ------------- standalone transpose+convert (fallback only) -------------
__global__ void transcvt(const float* __restrict__ in, ushort* __restrict__ out,
                         int R, int C) {
  __shared__ float tile[32 * 33];
  int e = blockIdx.z;
  const float* src = in + (size_t)e * R * C;
  ushort* dst = out + (size_t)e * R * C;
  int c0 = blockIdx.x * 32, r0 = blockIdx.y * 32;
  int lr = threadIdx.x >> 5, lc = threadIdx.x & 31;
#pragma unroll
  for (int p = 0; p < 4; ++p)
    tile[(p * 8 + lr) * 33 + lc] = src[(size_t)(r0 + p * 8 + lr) * C + c0 + lc];
  __syncthreads();
#pragma unroll
  for (int p = 0; p < 4; ++p)
    dst[(size_t)(c0 + p * 8 + lr) * R + r0 + lc] = f2bf(tile[lc * 33 + p * 8 + lr]);
}

// ---- prep: 64x64 f32->bf16 transpose tiles (W1T [0,8192), W2T [8192,16384))
// ---- + router (blocks 16384..18431)
__global__ void prep(const float* __restrict__ W1, ushort* __restrict__ W1T,
                     const float* __restrict__ W2, ushort* __restrict__ W2T,
                     int do_w2,
                     const float* __restrict__ x, const float* __restrict__ Wr,
                     const float* __restrict__ br, float* __restrict__ probs,
                     int* __restrict__ e_sel, float* __restrict__ w_sel,
                     ushort* __restrict__ xb) {
  __shared__ float tile[64 * 65];
  int b = blockIdx.x;
  int tid = threadIdx.x;
  if (b < 16384) {
    const float* src;
    ushort* dst;
    size_t sstride, dstride;
    if (b < 8192) {             // W1[e][d][f] -> W1T[e][f][d]
      int cx = b & 63, ry = (b >> 6) & 15, e = b >> 10;
      src = W1 + ((size_t)e * Dm + ry * 64) * Fm + cx * 64;
      dst = W1T + ((size_t)e * Fm + cx * 64) * Dm + ry * 64;
      sstride = Fm; dstride = Dm;
    } else {                    // W2[e][f][d] -> W2T[e][d][f]
      if (!do_w2) return;
      int j = b - 8192;
      int cx = j & 15, ry = (j >> 4) & 63, e = j >> 10;
      src = W2 + ((size_t)e * Fm + ry * 64) * Dm + cx * 64;
      dst = W2T + ((size_t)e * Dm + cx * 64) * Fm + ry * 64;
      sstride = Dm; dstride = Fm;
    }
    int lr = tid >> 4, lc4 = (tid & 15) * 4;
#pragma unroll
    for (int p = 0; p < 4; ++p) {
      float4 v = *(const float4*)(src + (size_t)(p * 16 + lr) * sstride + lc4);
      tile[(p * 16 + lr) * 65 + lc4] = v.x;
      tile[(p * 16 + lr) * 65 + lc4 + 1] = v.y;
      tile[(p * 16 + lr) * 65 + lc4 + 2] = v.z;
      tile[(p * 16 + lr) * 65 + lc4 + 3] = v.w;
    }
    __syncthreads();
#pragma unroll
    for (int p = 0; p < 4; ++p) {
      int oc = p * 16 + lr;     // source col = dest row
      ushort4 o;
      o.x = f2bf(tile[(lc4 + 0) * 65 + oc]);
      o.y = f2bf(tile[(lc4 + 1) * 65 + oc]);
      o.z = f2bf(tile[(lc4 + 2) * 65 + oc]);
      o.w = f2bf(tile[(lc4 + 3) * 65 + oc]);
      *(ushort4*)(dst + (size_t)oc * dstride + lc4) = o;
    }
    return;
  }
  int t = b - 16384;
  const float4* xr4 = (const float4*)(x + (size_t)t * Dm);
  float4 v = xr4[tid];
  ushort4 o;
  o.x = f2bf(v.x); o.y = f2bf(v.y); o.z = f2bf(v.z); o.w = f2bf(v.w);
  ((ushort4*)(xb + (size_t)t * Dm))[tid] = o;

  int d0 = tid * 4;
  const float4* wr4 = (const float4*)(Wr + (size_t)d0 * Em);
  float wv[4][8];
#pragma unroll
  for (int r = 0; r < 4; ++r) {
    float4 a = wr4[r * 2], bq = wr4[r * 2 + 1];
    wv[r][0] = a.x; wv[r][1] = a.y; wv[r][2] = a.z; wv[r][3] = a.w;
    wv[r][4] = bq.x; wv[r][5] = bq.y; wv[r][6] = bq.z; wv[r][7] = bq.w;
  }
  float xs[4] = {v.x, v.y, v.z, v.w};
  float acc[Em];
#pragma unroll
  for (int e = 0; e < Em; ++e)
    acc[e] = xs[0] * wv[0][e] + xs[1] * wv[1][e] + xs[2] * wv[2][e] + xs[3] * wv[3][e];
#pragma unroll
  for (int off = 32; off >= 1; off >>= 1)
#pragma unroll
    for (int e = 0; e < Em; ++e) acc[e] += __shfl_down(acc[e], off);
  float* red = tile;
  int lane = tid & 63, wid = tid >> 6;
  if (lane == 0)
#pragma unroll
    for (int e = 0; e < Em; ++e) red[wid * 8 + e] = acc[e];
  __syncthreads();
  if (tid == 0) {
    float lg[Em];
#pragma unroll
    for (int e = 0; e < Em; ++e)
      lg[e] = red[e] + red[8 + e] + red[16 + e] + red[24 + e] + br[e];
    int i0 = 0;
    for (int e = 1; e < Em; ++e) if (lg[e] > lg[i0]) i0 = e;
    int i1 = -1;
    for (int e = 0; e < Em; ++e) {
      if (e == i0) continue;
      if (i1 < 0 || lg[e] > lg[i1]) i1 = e;
    }
    float d = lg[i1] - lg[i0];
    float tt = expf(d);
    float inv = 1.f / (1.f + tt);
    probs[t * 2] = inv; probs[t * 2 + 1] = tt * inv;
    e_sel[t * 2] = i0; e_sel[t * 2 + 1] = i1;
    w_sel[t * 2] = inv; w_sel[t * 2 + 1] = tt * inv;
  }
}

// ---------------- stable per-expert list build (1 block, 256 thr) ----------------
__global__ void build_lists(const int* __restrict__ e_sel, const float* __restrict__ w_sel,
                            int* __restrict__ tok_of_row, float* __restrict__ w_of_row,
                            int* __restrict__ base, int* __restrict__ npad) {
  __shared__ int cnt[Em], run[Em], sbase[Em];
  __shared__ int wsum[4][Em];
  int tid = threadIdx.x, lane = tid & 63, wid = tid >> 6;
  if (tid < Em) { cnt[tid] = 0; run[tid] = 0; }
  __syncthreads();
  for (int t = tid; t < TOKENS; t += 256) {
    atomicAdd(&cnt[e_sel[2 * t]], 1);
    atomicAdd(&cnt[e_sel[2 * t + 1]], 1);
  }
  __syncthreads();
  if (tid == 0) {
    int b = 0;
    for (int e = 0; e < Em; ++e) {
      base[e] = b; sbase[e] = b;
      int n = cnt[e];
      int p = (n + 127) & ~127;
      npad[e] = p; b += p;
    }
  }
  __syncthreads();
  for (int c = 0; c < TOKENS / 256; ++c) {
    int t = c * 256 + tid;
    int e0 = e_sel[2 * t], e1 = e_sel[2 * t + 1];
    unsigned long long mm[Em];
#pragma unroll
    for (int e = 0; e < Em; ++e) {
      unsigned long long m0 = __ballot(e0 == e);
      unsigned long long m1 = __ballot(e1 == e);
      mm[e] = m0 | m1;
      if (lane == 0) wsum[wid][e] = __popcll(mm[e]);
    }
    __syncthreads();
    unsigned long long below = (1ull << lane) - 1ull;
    {
      int e = e0;
      int p = __popcll(mm[e] & below);
      int pre = 0;
      for (int w = 0; w < wid; ++w) pre += wsum[w][e];
      int row = sbase[e] + run[e] + pre + p;
      tok_of_row[row] = t; w_of_row[row] = w_sel[2 * t];
    }
    {
      int e = e1;
      int p = __popcll(mm[e] & below);
      int pre = 0;
      for (int w = 0; w < wid; ++w) pre += wsum[w][e];
      int row = sbase[e] + run[e] + pre + p;
      tok_of_row[row] = t; w_of_row[row] = w_sel[2 * t + 1];
    }
    __syncthreads();
    if (tid < Em) {
      int s = 0;
      for (int w = 0; w < 4; ++w) s += wsum[w][tid];
      run[tid] += s;
    }
    __syncthreads();
  }
  for (int e = 0; e < Em; ++e) {
    int n = cnt[e];
    int p = (n + 127) & ~127;
    for (int i = n + tid; i < p; i += 256) {
      tok_of_row[sbase[e] + i] = -1;
      w_of_row[sbase[e] + i] = 0.f;
    }
  }
}

// ---- GEMM1: H = gelu(Xg @ W1T^T + b1); BK=32, simple 2-barrier loop (R2) ----
// grid (x = n-tile [32], y = e*16+rt [128]); 32 K-tiles
__global__ __launch_bounds__(256) void gemm1(
    const ushort* __restrict__ xb, const ushort* __restrict__ W1T,
    const float* __restrict__ b1, ushort* __restrict__ H,
    const int* __restrict__ tok_of_row, const int* __restrict__ base,
    const int* __restrict__ npad) {
  __shared__ ushort sbuf[8192];   // A elems [0,4096), B [4096,8192); epilogue reuse
  __shared__ int toks[128];
  int tid = threadIdx.x, lane = tid & 63, wid = tid >> 6;
  int e = blockIdx.y >> 4, rt = blockIdx.y & 15;
  int nt = npad[e] >> 7;
  if (rt >= nt) return;
  int row0 = base[e] + rt * 128;
  int n0 = blockIdx.x * 128;
  if (tid < 128) toks[tid] = tok_of_row[row0 + tid];
  __syncthreads();
  int arow = tid >> 2, asub = tid & 3;
  int sw = ((asub ^ ((arow >> 1) & 3)) << 3);   // XOR-swizzled source chunk
  int t0 = toks[arow];      if (t0 < 0) t0 = 0;
  int t1 = toks[64 + arow]; if (t1 < 0) t1 = 0;
  const ushort* sA0 = xb + (size_t)t0 * Dm + sw;
  const ushort* sA1 = xb + (size_t)t1 * Dm + sw;
  const ushort* sB0 = W1T + ((size_t)e * Fm + n0 + arow) * Dm + sw;
  const ushort* sB1 = sB0 + (size_t)64 * Dm;
  int wr2 = wid >> 1, wc2 = wid & 1;
  int g = lane >> 4, c = (lane >> 1) & 3;       // read-side XOR
  int aidx = (wr2 * 64 + (lane & 15)) * 32 + ((g ^ c) << 3);
  int bidx = (wc2 * 64 + (lane & 15)) * 32 + ((g ^ c) << 3);
  f32x4 acc[4][4] = {};
  for (int kt = 0; kt < Dm / 32; ++kt) {
    STAGE4()
    __syncthreads();
    kstep(sbuf, aidx, bidx, acc);
    __syncthreads();
  }
  // epilogue: gelu -> 2-pass LDS staging (64x128, full sbuf) -> coalesced stores
#pragma unroll
  for (int p = 0; p < 2; ++p) {
    if (wr2 == p) {
#pragma unroll
      for (int n = 0; n < 4; ++n) {
        int col = wc2 * 64 + (lane & 15) + n * 16;
        float bias = b1[e * Fm + n0 + col];
#pragma unroll
        for (int m = 0; m < 4; ++m) {
#pragma unroll
          for (int j = 0; j < 4; ++j) {
            float v = acc[m][n][j] + bias;
            float gl = 0.5f * v * (1.f + erff(v * 0.70710678118654752f));
            sbuf[(g * 4 + m * 16 + j) * 128 + col] = f2bf(gl);
          }
        }
      }
    }
    __syncthreads();
#pragma unroll
    for (int q = 0; q < 4; ++q) {
      int id = q * 256 + tid;
      int r = id >> 4, ch = id & 15;
      *(s16x8*)(H + (size_t)(row0 + p * 64 + r) * Fm + n0 + ch * 8) =
          *(const s16x8*)(sbuf + r * 128 + ch * 8);
    }
    __syncthreads();
  }
}

// ---- GEMM2: out[tok] += w*(H @ W2T^T + b2); BK=32, simple loop, split-K=4 ----
// grid (x = n-tile [8], y = e*16+rt [128], z = k-quarter [4]); 32 K-tiles/slice
__global__ __launch_bounds__(256) void gemm2(
    const ushort* __restrict__ H, const ushort* __restrict__ W2T,
    const float* __restrict__ b2,
    const int* __restrict__ tok_of_row, const float* __restrict__ w_of_row,
    const int* __restrict__ base, const int* __restrict__ npad,
    float* __restrict__ out) {
  __shared__ ushort sbuf[8192];
  __shared__ int toks[128];
  __shared__ float wts[128];
  int tid = threadIdx.x, lane = tid & 63, wid = tid >> 6;
  int e = blockIdx.y >> 4, rt = blockIdx.y & 15;
  int nt = npad[e] >> 7;
  if (rt >= nt) return;
  int row0 = base[e] + rt * 128;
  int n0 = blockIdx.x * 128;
  int k0 = blockIdx.z * (Fm / 4);
  if (tid < 128) {
    toks[tid] = tok_of_row[row0 + tid];
    wts[tid] = w_of_row[row0 + tid];
  }
  __syncthreads();
  int arow = tid >> 2, asub = tid & 3;
  int sw = ((asub ^ ((arow >> 1) & 3)) << 3);
  const ushort* sA0 = H + (size_t)(row0 + arow) * Fm + k0 + sw;
  const ushort* sA1 = sA0 + (size_t)64 * Fm;
  const ushort* sB0 = W2T + ((size_t)e * Dm + n0 + arow) * Fm + k0 + sw;
  const ushort* sB1 = sB0 + (size_t)64 * Fm;
  int wr2 = wid >> 1, wc2 = wid & 1;
  int g = lane >> 4, c = (lane >> 1) & 3;
  int aidx = (wr2 * 64 + (lane & 15)) * 32 + ((g ^ c) << 3);
  int bidx = (wc2 * 64 + (lane & 15)) * 32 + ((g ^ c) << 3);
  f32x4 acc[4][4] = {};
  for (int kt = 0; kt < Fm / 4 / 32; ++kt) {
    STAGE4()
    __syncthreads();
    kstep(sbuf, aidx, bidx, acc);
    __syncthreads();
  }
  int rb = wr2 * 64 + g * 4;
  int cb = n0 + wc2 * 64 + (lane & 15);
  int add_bias = (blockIdx.z == 0);
#pragma unroll
  for (int n = 0; n < 4; ++n) {
    int col = cb + n * 16;
    float bias = add_bias ? b2[e * Dm + col] : 0.f;
#pragma unroll
    for (int m = 0; m < 4; ++m) {
      int rl = rb + m * 16;
#pragma unroll
      for (int j = 0; j < 4; ++j) {
        int tok = toks[rl + j];
        if (tok >= 0)
          atomicAdd(&out[(size_t)tok * Dm + col], wts[rl + j] * (acc[m][n][j] + bias));
      }
    }
  }
}

extern "C" void kernel_launch(void* const* d_in, const int* in_sizes, int n_in,
                              void* d_out, int out_size, void* d_ws, size_t ws_size,
                              hipStream_t stream) {
  const float* x  = (const float*)d_in[0];
  const float* Wr = (const float*)d_in[1];
  const float* br = (const float*)d_in[2];
  const float* W1 = (const float*)d_in[3];
  const float* b1 = (const float*)d_in[4];
  const float* W2 = (const float*)d_in[5];
  const float* b2 = (const float*)d_in[6];
  float* out = (float*)d_out;
  float* probs = out + (size_t)TOKENS * Dm;

  char* ws = (char*)d_ws;
  ushort* W1T  = (ushort*)ws;                          // 67,108,864 B
  ushort* Hbuf = (ushort*)(ws + 67108864);             // 41,943,040 B (5120 rows)
  ushort* xb   = (ushort*)(ws + 109051904);            //  4,194,304 B
  int*   tok_of_row = (int*)(ws + 113246208);
  float* w_of_row   = (float*)(ws + 113266688);
  int*   e_sel      = (int*)(ws + 113287168);
  float* w_sel      = (float*)(ws + 113303552);
  int*   meta       = (int*)(ws + 113319936);          // base[8], npad[8]
  int sep = (ws_size >= 180429056ULL) ? 1 : 0;
  ushort* W2T = sep ? (ushort*)(ws + 113320192) : W1T;

  hipMemsetAsync(out, 0, (size_t)TOKENS * Dm * sizeof(float), stream);
  prep<<<16384 + TOKENS, 256, 0, stream>>>(W1, W1T, W2, W2T, sep, x, Wr, br,
                                           probs, e_sel, w_sel, xb);
  build_lists<<<1, 256, 0, stream>>>(e_sel, w_sel, tok_of_row, w_of_row,
                                     meta, meta + 8);
  gemm1<<<dim3(32, 128), 256, 0, stream>>>(xb, W1T, b1, Hbuf, tok_of_row,
                                           meta, meta + 8);
  if (!sep)
    transcvt<<<dim3(Dm / 32, Fm / 32, Em), 256, 0, stream>>>(W2, W2T, Fm, Dm);
  gemm2<<<dim3(8, 128, 4), 256, 0, stream>>>(Hbuf, W2T, b2, tok_of_row, w_of_row,
                                             meta, meta + 8, out);
}

// Round 10
// 323.745 us; speedup vs baseline: 1.0658x; 1.0658x over previous
//
#include <hip/hip_runtime.h>
#include <hip/hip_bf16.h>
#include <cstdint>

#define TOKENS 2048
#define Dm 1024
#define Fm 4096
#define Em 8

typedef short s16x8 __attribute__((ext_vector_type(8)));
typedef float f32x4 __attribute__((ext_vector_type(4)));

#define GLOAD16(g, l) __builtin_amdgcn_global_load_lds(                     \
    (const __attribute__((address_space(1))) void*)(g),                     \
    (__attribute__((address_space(3))) void*)(l), 16, 0, 0)

__device__ __forceinline__ ushort f2bf(float f) {
  union { float f; uint32_t u; } v; v.f = f;
  uint32_t r = v.u + 0x7fffu + ((v.u >> 16) & 1u);
  return (ushort)(r >> 16);
}

// ------------- standalone transpose+convert (fallback only) -------------
__global__ void transcvt(const float* __restrict__ in, ushort* __restrict__ out,
                         int R, int C) {
  __shared__ float tile[32 * 33];
  int e = blockIdx.z;
  const float* src = in + (size_t)e * R * C;
  ushort* dst = out + (size_t)e * R * C;
  int c0 = blockIdx.x * 32, r0 = blockIdx.y * 32;
  int lr = threadIdx.x >> 5, lc = threadIdx.x & 31;
#pragma unroll
  for (int p = 0; p < 4; ++p)
    tile[(p * 8 + lr) * 33 + lc] = src[(size_t)(r0 + p * 8 + lr) * C + c0 + lc];
  __syncthreads();
#pragma unroll
  for (int p = 0; p < 4; ++p)
    dst[(size_t)(c0 + p * 8 + lr) * R + r0 + lc] = f2bf(tile[lc * 33 + p * 8 + lr]);
}

// ---- prep (R5 shape): W1T tiles [0,32768) + W2T tiles [32768,65536) + router ----
__global__ void prep(const float* __restrict__ W1, ushort* __restrict__ W1T,
                     const float* __restrict__ W2, ushort* __restrict__ W2T,
                     int do_w2,
                     const float* __restrict__ x, const float* __restrict__ Wr,
                     const float* __restrict__ br, float* __restrict__ probs,
                     int* __restrict__ e_sel, float* __restrict__ w_sel,
                     ushort* __restrict__ xb) {
  __shared__ float shf[32 * 33];
  int b = blockIdx.x;
  if (b < 65536) {
    const float* src;
    ushort* dst;
    size_t sstride, dstride;
    if (b < 32768) {            // W1[e][d][f] -> W1T[e][f][d]
      int cx = b & 127, ry = (b >> 7) & 31, e = b >> 12;
      src = W1 + ((size_t)e * Dm + ry * 32) * Fm + cx * 32;
      dst = W1T + ((size_t)e * Fm + cx * 32) * Dm + ry * 32;
      sstride = Fm; dstride = Dm;
    } else {                    // W2[e][f][d] -> W2T[e][d][f]
      if (!do_w2) return;
      int b2i = b - 32768;
      int cx = b2i & 31, ry = (b2i >> 5) & 127, e = b2i >> 12;
      src = W2 + ((size_t)e * Fm + ry * 32) * Dm + cx * 32;
      dst = W2T + ((size_t)e * Dm + cx * 32) * Fm + ry * 32;
      sstride = Dm; dstride = Fm;
    }
    int lr = threadIdx.x >> 5, lc = threadIdx.x & 31;
#pragma unroll
    for (int p = 0; p < 4; ++p)
      shf[(p * 8 + lr) * 33 + lc] = src[(size_t)(p * 8 + lr) * sstride + lc];
    __syncthreads();
#pragma unroll
    for (int p = 0; p < 4; ++p)
      dst[(size_t)(p * 8 + lr) * dstride + lc] = f2bf(shf[lc * 33 + p * 8 + lr]);
    return;
  }
  int t = b - 65536;
  int tid = threadIdx.x;
  const float4* xr4 = (const float4*)(x + (size_t)t * Dm);
  float4 v = xr4[tid];
  ushort4 o;
  o.x = f2bf(v.x); o.y = f2bf(v.y); o.z = f2bf(v.z); o.w = f2bf(v.w);
  ((ushort4*)(xb + (size_t)t * Dm))[tid] = o;

  int d0 = tid * 4;
  const float4* wr4 = (const float4*)(Wr + (size_t)d0 * Em);
  float wv[4][8];
#pragma unroll
  for (int r = 0; r < 4; ++r) {
    float4 a = wr4[r * 2], bq = wr4[r * 2 + 1];
    wv[r][0] = a.x; wv[r][1] = a.y; wv[r][2] = a.z; wv[r][3] = a.w;
    wv[r][4] = bq.x; wv[r][5] = bq.y; wv[r][6] = bq.z; wv[r][7] = bq.w;
  }
  float xs[4] = {v.x, v.y, v.z, v.w};
  float acc[Em];
#pragma unroll
  for (int e = 0; e < Em; ++e)
    acc[e] = xs[0] * wv[0][e] + xs[1] * wv[1][e] + xs[2] * wv[2][e] + xs[3] * wv[3][e];
#pragma unroll
  for (int off = 32; off >= 1; off >>= 1)
#pragma unroll
    for (int e = 0; e < Em; ++e) acc[e] += __shfl_down(acc[e], off);
  float* red = shf;
  int lane = tid & 63, wid = tid >> 6;
  if (lane == 0)
#pragma unroll
    for (int e = 0; e < Em; ++e) red[wid * 8 + e] = acc[e];
  __syncthreads();
  if (tid == 0) {
    float lg[Em];
#pragma unroll
    for (int e = 0; e < Em; ++e)
      lg[e] = red[e] + red[8 + e] + red[16 + e] + red[24 + e] + br[e];
    int i0 = 0;
    for (int e = 1; e < Em; ++e) if (lg[e] > lg[i0]) i0 = e;
    int i1 = -1;
    for (int e = 0; e < Em; ++e) {
      if (e == i0) continue;
      if (i1 < 0 || lg[e] > lg[i1]) i1 = e;
    }
    float d = lg[i1] - lg[i0];
    float tt = expf(d);
    float inv = 1.f / (1.f + tt);
    probs[t * 2] = inv; probs[t * 2 + 1] = tt * inv;
    e_sel[t * 2] = i0; e_sel[t * 2 + 1] = i1;
    w_sel[t * 2] = inv; w_sel[t * 2 + 1] = tt * inv;
  }
}

// ---------------- stable per-expert list build (1 block, 256 thr) ----------------
__global__ void build_lists(const int* __restrict__ e_sel, const float* __restrict__ w_sel,
                            int* __restrict__ tok_of_row, float* __restrict__ w_of_row,
                            int* __restrict__ base, int* __restrict__ npad) {
  __shared__ int cnt[Em], run[Em], sbase[Em];
  __shared__ int wsum[4][Em];
  int tid = threadIdx.x, lane = tid & 63, wid = tid >> 6;
  if (tid < Em) { cnt[tid] = 0; run[tid] = 0; }
  __syncthreads();
  for (int t = tid; t < TOKENS; t += 256) {
    atomicAdd(&cnt[e_sel[2 * t]], 1);
    atomicAdd(&cnt[e_sel[2 * t + 1]], 1);
  }
  __syncthreads();
  if (tid == 0) {
    int b = 0;
    for (int e = 0; e < Em; ++e) {
      base[e] = b; sbase[e] = b;
      int n = cnt[e];
      int p = (n + 127) & ~127;
      npad[e] = p; b += p;
    }
  }
  __syncthreads();
  for (int c = 0; c < TOKENS / 256; ++c) {
    int t = c * 256 + tid;
    int e0 = e_sel[2 * t], e1 = e_sel[2 * t + 1];
    unsigned long long mm[Em];
#pragma unroll
    for (int e = 0; e < Em; ++e) {
      unsigned long long m0 = __ballot(e0 == e);
      unsigned long long m1 = __ballot(e1 == e);
      mm[e] = m0 | m1;
      if (lane == 0) wsum[wid][e] = __popcll(mm[e]);
    }
    __syncthreads();
    unsigned long long below = (1ull << lane) - 1ull;
    {
      int e = e0;
      int p = __popcll(mm[e] & below);
      int pre = 0;
      for (int w = 0; w < wid; ++w) pre += wsum[w][e];
      int row = sbase[e] + run[e] + pre + p;
      tok_of_row[row] = t; w_of_row[row] = w_sel[2 * t];
    }
    {
      int e = e1;
      int p = __popcll(mm[e] & below);
      int pre = 0;
      for (int w = 0; w < wid; ++w) pre += wsum[w][e];
      int row = sbase[e] + run[e] + pre + p;
      tok_of_row[row] = t; w_of_row[row] = w_sel[2 * t + 1];
    }
    __syncthreads();
    if (tid < Em) {
      int s = 0;
      for (int w = 0; w < 4; ++w) s += wsum[w][tid];
      run[tid] += s;
    }
    __syncthreads();
  }
  for (int e = 0; e < Em; ++e) {
    int n = cnt[e];
    int p = (n + 127) & ~127;
    for (int i = n + tid; i < p; i += 256) {
      tok_of_row[sbase[e] + i] = -1;
      w_of_row[sbase[e] + i] = 0.f;
    }
  }
}

// ---- GEMM1 (exact R2 core): H = gelu(Xg @ W1T^T + b1) ----
// grid (x = n-tile [32], y = e*16+rt [128])
__global__ __launch_bounds__(256) void gemm1(
    const ushort* __restrict__ xb, const ushort* __restrict__ W1T,
    const float* __restrict__ b1, ushort* __restrict__ H,
    const int* __restrict__ tok_of_row, const int* __restrict__ base,
    const int* __restrict__ npad) {
  int e = blockIdx.y >> 4, rt = blockIdx.y & 15;
  int np = npad[e];
  if (rt * 128 >= np) return;
  int row0 = base[e] + rt * 128;
  int n0 = blockIdx.x * 128;
  __shared__ ushort As[128 * 32];
  __shared__ ushort Bs[128 * 32];
  __shared__ int toks[128];
  int tid = threadIdx.x, lane = tid & 63, wid = tid >> 6;
  if (tid < 128) toks[tid] = tok_of_row[row0 + tid];
  __syncthreads();
  int arow = tid >> 2, asub = tid & 3;
  int t0 = toks[arow];      if (t0 < 0) t0 = 0;
  int t1 = toks[64 + arow]; if (t1 < 0) t1 = 0;
  const ushort* sA0 = xb + (size_t)t0 * Dm + asub * 8;
  const ushort* sA1 = xb + (size_t)t1 * Dm + asub * 8;
  const ushort* sB0 = W1T + ((size_t)e * Fm + n0 + arow) * Dm + asub * 8;
  const ushort* sB1 = sB0 + (size_t)64 * Dm;
  char* ldA0 = (char*)As + wid * 1024;
  char* ldA1 = (char*)As + 4096 + wid * 1024;
  char* ldB0 = (char*)Bs + wid * 1024;
  char* ldB1 = (char*)Bs + 4096 + wid * 1024;
  int wr = wid >> 1, wc = wid & 1;
  const ushort* aB = As + ((size_t)(wr * 64 + (lane & 15)) * 32) + (lane >> 4) * 8;
  const ushort* bB = Bs + ((size_t)(wc * 64 + (lane & 15)) * 32) + (lane >> 4) * 8;
  f32x4 acc[4][4] = {};
  for (int kt = 0; kt < Dm / 32; ++kt) {
    GLOAD16(sA0, ldA0);
    GLOAD16(sA1, ldA1);
    GLOAD16(sB0, ldB0);
    GLOAD16(sB1, ldB1);
    sA0 += 32; sA1 += 32; sB0 += 32; sB1 += 32;
    __syncthreads();
    s16x8 av[4], bv[4];
#pragma unroll
    for (int m = 0; m < 4; ++m) av[m] = *(const s16x8*)(aB + m * 512);
#pragma unroll
    for (int n = 0; n < 4; ++n) bv[n] = *(const s16x8*)(bB + n * 512);
#pragma unroll
    for (int m = 0; m < 4; ++m)
#pragma unroll
      for (int n = 0; n < 4; ++n)
        acc[m][n] = __builtin_amdgcn_mfma_f32_16x16x32_bf16(av[m], bv[n], acc[m][n], 0, 0, 0);
    __syncthreads();
  }
  int rb = wr * 64 + ((lane >> 4) << 2);
  int cb = n0 + wc * 64 + (lane & 15);
#pragma unroll
  for (int n = 0; n < 4; ++n) {
    int col = cb + n * 16;
    float bias = b1[e * Fm + col];
#pragma unroll
    for (int m = 0; m < 4; ++m) {
      int r = row0 + rb + m * 16;
#pragma unroll
      for (int j = 0; j < 4; ++j) {
        float v = acc[m][n][j] + bias;
        float g = 0.5f * v * (1.f + erff(v * 0.70710678118654752f));
        H[(size_t)(r + j) * Fm + col] = f2bf(g);
      }
    }
  }
}

// ---- GEMM2 (exact R2 core + split-K=4 + fused b2): out[tok] += w*(H@W2T^T+b2) ----
// grid (x = n-tile [8], y = e*16+rt [128], z = k-quarter [4])
__global__ __launch_bounds__(256) void gemm2(
    const ushort* __restrict__ H, const ushort* __restrict__ W2T,
    const float* __restrict__ b2,
    const int* __restrict__ tok_of_row, const float* __restrict__ w_of_row,
    const int* __restrict__ base, const int* __restrict__ npad,
    float* __restrict__ out) {
  int e = blockIdx.y >> 4, rt = blockIdx.y & 15;
  int np = npad[e];
  if (rt * 128 >= np) return;
  int row0 = base[e] + rt * 128;
  int n0 = blockIdx.x * 128;
  int k0 = blockIdx.z * (Fm / 4);
  __shared__ ushort As[128 * 32];
  __shared__ ushort Bs[128 * 32];
  __shared__ int toks[128];
  __shared__ float wts[128];
  int tid = threadIdx.x, lane = tid & 63, wid = tid >> 6;
  if (tid < 128) {
    toks[tid] = tok_of_row[row0 + tid];
    wts[tid] = w_of_row[row0 + tid];
  }
  __syncthreads();
  int arow = tid >> 2, asub = tid & 3;
  const ushort* sA0 = H + (size_t)(row0 + arow) * Fm + k0 + asub * 8;
  const ushort* sA1 = sA0 + (size_t)64 * Fm;
  const ushort* sB0 = W2T + ((size_t)e * Dm + n0 + arow) * Fm + k0 + asub * 8;
  const ushort* sB1 = sB0 + (size_t)64 * Fm;
  char* ldA0 = (char*)As + wid * 1024;
  char* ldA1 = (char*)As + 4096 + wid * 1024;
  char* ldB0 = (char*)Bs + wid * 1024;
  char* ldB1 = (char*)Bs + 4096 + wid * 1024;
  int wr = wid >> 1, wc = wid & 1;
  const ushort* aB = As + ((size_t)(wr * 64 + (lane & 15)) * 32) + (lane >> 4) * 8;
  const ushort* bB = Bs + ((size_t)(wc * 64 + (lane & 15)) * 32) + (lane >> 4) * 8;
  f32x4 acc[4][4] = {};
  for (int kt = 0; kt < Fm / 4 / 32; ++kt) {
    GLOAD16(sA0, ldA0);
    GLOAD16(sA1, ldA1);
    GLOAD16(sB0, ldB0);
    GLOAD16(sB1, ldB1);
    sA0 += 32; sA1 += 32; sB0 += 32; sB1 += 32;
    __syncthreads();
    s16x8 av[4], bv[4];
#pragma unroll
    for (int m = 0; m < 4; ++m) av[m] = *(const s16x8*)(aB + m * 512);
#pragma unroll
    for (int n = 0; n < 4; ++n) bv[n] = *(const s16x8*)(bB + n * 512);
#pragma unroll
    for (int m = 0; m < 4; ++m)
#pragma unroll
      for (int n = 0; n < 4; ++n)
        acc[m][n] = __builtin_amdgcn_mfma_f32_16x16x32_bf16(av[m], bv[n], acc[m][n], 0, 0, 0);
    __syncthreads();
  }
  int rb = wr * 64 + ((lane >> 4) << 2);
  int cb = n0 + wc * 64 + (lane & 15);
  int add_bias = (blockIdx.z == 0);
#pragma unroll
  for (int n = 0; n < 4; ++n) {
    int col = cb + n * 16;
    float bias = add_bias ? b2[e * Dm + col] : 0.f;
#pragma unroll
    for (int m = 0; m < 4; ++m) {
      int rl = rb + m * 16;
#pragma unroll
      for (int j = 0; j < 4; ++j) {
        int tok = toks[rl + j];
        if (tok >= 0)
          atomicAdd(&out[(size_t)tok * Dm + col], wts[rl + j] * (acc[m][n][j] + bias));
      }
    }
  }
}

extern "C" void kernel_launch(void* const* d_in, const int* in_sizes, int n_in,
                              void* d_out, int out_size, void* d_ws, size_t ws_size,
                              hipStream_t stream) {
  const float* x  = (const float*)d_in[0];
  const float* Wr = (const float*)d_in[1];
  const float* br = (const float*)d_in[2];
  const float* W1 = (const float*)d_in[3];
  const float* b1 = (const float*)d_in[4];
  const float* W2 = (const float*)d_in[5];
  const float* b2 = (const float*)d_in[6];
  float* out = (float*)d_out;
  float* probs = out + (size_t)TOKENS * Dm;

  char* ws = (char*)d_ws;
  ushort* W1T  = (ushort*)ws;                          // 67,108,864 B
  ushort* Hbuf = (ushort*)(ws + 67108864);             // 41,943,040 B (5120 rows)
  ushort* xb   = (ushort*)(ws + 109051904);            //  4,194,304 B
  int*   tok_of_row = (int*)(ws + 113246208);
  float* w_of_row   = (float*)(ws + 113266688);
  int*   e_sel      = (int*)(ws + 113287168);
  float* w_sel      = (float*)(ws + 113303552);
  int*   meta       = (int*)(ws + 113319936);          // base[8], npad[8]
  int sep = (ws_size >= 180429056ULL) ? 1 : 0;
  ushort* W2T = sep ? (ushort*)(ws + 113320192) : W1T;

  hipMemsetAsync(out, 0, (size_t)TOKENS * Dm * sizeof(float), stream);
  prep<<<65536 + TOKENS, 256, 0, stream>>>(W1, W1T, W2, W2T, sep, x, Wr, br,
                                           probs, e_sel, w_sel, xb);
  build_lists<<<1, 256, 0, stream>>>(e_sel, w_sel, tok_of_row, w_of_row,
                                     meta, meta + 8);
  gemm1<<<dim3(32, 128), 256, 0, stream>>>(xb, W1T, b1, Hbuf, tok_of_row,
                                           meta, meta + 8);
  if (!sep)
    transcvt<<<dim3(Dm / 32, Fm / 32, Em), 256, 0, stream>>>(W2, W2T, Fm, Dm);
  gemm2<<<dim3(8, 128, 4), 256, 0, stream>>>(Hbuf, W2T, b2, tok_of_row, w_of_row,
                                             meta, meta + 8, out);
}